// Round 17
// baseline (19162.341 us; speedup 1.0000x reference)
//
#include <hip/hip_runtime.h>

// SingleLayerRNN — Round 17: hoist x@Wih out of the serial loop.
// Phase A (parallel, ~0.7ms): dotX[t][b][j] = cx0+cx1 for all t (frozen chain
//   order: cx0 = fmaf chain k=0..511 ascending, cx1 = 512..1023, sum).
// Phase B (persistent): per step only h-chains + combine:
//   s = dotX + (ch0+ch1); h' = tanh_T2(s)   [frozen R8 order]
// Evidence: R13-16 invariant 32us/step across 4 h-exchange mechanisms =>
// per-step work structure is the cost; halve it and shrink h traffic
// (512->256 blocks, 16.5->8 MB/step). Barrier kept verbatim (isolating).
// ws needs ~139MB; falls back to proven R15 path (16.3ms) if smaller.

#define TSTEPS 512
#define BATCH  64
#define HID    1024
#define NELEM  65536
#define LROW   1028     // padded LDS row stride (floats)

__device__ __forceinline__ float tanh_T2(float x) {
#pragma clang fp contract(off)
    const float C = 7.99881172180175781f;
    float ax = fabsf(x);
    float xc = fminf(fmaxf(x, -C), C);
    float x2 = xc * xc;
    float num = -2.76076847742355e-16f;
    num = __builtin_fmaf(x2, num, 2.00018790482477e-13f);
    num = __builtin_fmaf(x2, num, -8.60467152213735e-11f);
    num = __builtin_fmaf(x2, num, 5.12229709037114e-08f);
    num = __builtin_fmaf(x2, num, 1.48572235717979e-05f);
    num = __builtin_fmaf(x2, num, 6.37261928875436e-04f);
    num = __builtin_fmaf(x2, num, 4.89352455891786e-03f);
    num = xc * num;
    float den = 1.19825839466702e-06f;
    den = __builtin_fmaf(x2, den, 1.18534705686654e-04f);
    den = __builtin_fmaf(x2, den, 2.26843463243900e-03f);
    den = __builtin_fmaf(x2, den, 4.89352518554385e-03f);
    float r = num / den;
    return (ax < 0.0004f) ? x : r;
}

// W [k][j] -> WT [j][k]  (bit-exact data movement; verified R10/R12-R16)
__global__ __launch_bounds__(256) void transpose_w(const float* __restrict__ W,
                                                   float* __restrict__ WT) {
    __shared__ float tile[64][65];
    const int c0 = blockIdx.x * 64;
    const int r0 = blockIdx.y * 64;
    const int tx = threadIdx.x & 63;
    const int ty = threadIdx.x >> 6;
    #pragma unroll
    for (int r = 0; r < 16; ++r) {
        const int rr = r * 4 + ty;
        tile[rr][tx] = W[(size_t)(r0 + rr) * HID + c0 + tx];
    }
    __syncthreads();
    #pragma unroll
    for (int r = 0; r < 16; ++r) {
        const int rr = r * 4 + ty;
        WT[(size_t)(c0 + rr) * HID + r0 + tx] = tile[tx][rr];
    }
}

// ---- Phase A: dotX[t][b][j] = (cx0 + cx1), frozen chain order ----
// grid (16 jchunks, 4 bchunks16, 512 t), block 256 = (jq16 x i16);
// thread computes 4 j's for one (t, b).
__global__ __launch_bounds__(256) void gemm_x(
    const float* __restrict__ x,     // [512][64][1024]
    const float* __restrict__ Wih,   // [1024(k)][1024(j)] original layout
    float* __restrict__ dotX)        // [512][64][1024]
{
#pragma clang fp contract(off)
    __shared__ float xs[16 * LROW];  // 16 rows, padded

    const int t  = blockIdx.z;
    const int bc = blockIdx.y;       // 16-row chunk
    const int jb = blockIdx.x * 64;
    const int tid = threadIdx.x;

    // stage 16 rows of x_t (16384 floats) as float4
    {
        const float* xsrc = x + (size_t)t * NELEM + (size_t)(bc * 16) * HID;
        #pragma unroll
        for (int s = 0; s < 16; ++s) {
            const int f = tid + s * 256;       // float4 id 0..4095
            const int r = f >> 8, c4 = f & 255;
            const float4 v = ((const float4*)(xsrc + (size_t)r * HID))[c4];
            *(float4*)&xs[r * LROW + c4 * 4] = v;
        }
    }
    __syncthreads();

    const int jq = tid & 15;         // 4-j group
    const int i  = tid >> 4;         // row 0..15
    const int j0 = jb + jq * 4;
    const float* xr = xs + i * LROW;

    float a0[4] = {0.f, 0.f, 0.f, 0.f};
    float a1[4] = {0.f, 0.f, 0.f, 0.f};
    #pragma unroll 8
    for (int k = 0; k < 512; ++k) {
        const float4 w = *(const float4*)(Wih + (size_t)k * HID + j0);
        const float xv = xr[k];
        a0[0] = __builtin_fmaf(xv, w.x, a0[0]);
        a0[1] = __builtin_fmaf(xv, w.y, a0[1]);
        a0[2] = __builtin_fmaf(xv, w.z, a0[2]);
        a0[3] = __builtin_fmaf(xv, w.w, a0[3]);
    }
    #pragma unroll 8
    for (int k = 512; k < 1024; ++k) {
        const float4 w = *(const float4*)(Wih + (size_t)k * HID + j0);
        const float xv = xr[k];
        a1[0] = __builtin_fmaf(xv, w.x, a1[0]);
        a1[1] = __builtin_fmaf(xv, w.y, a1[1]);
        a1[2] = __builtin_fmaf(xv, w.z, a1[2]);
        a1[3] = __builtin_fmaf(xv, w.w, a1[3]);
    }
    float4 r;
    r.x = a0[0] + a1[0];             // cx0 + cx1 (frozen combine)
    r.y = a0[1] + a1[1];
    r.z = a0[2] + a1[2];
    r.w = a0[3] + a1[3];
    *(float4*)(dotX + (size_t)t * NELEM + (size_t)(bc * 16 + i) * HID + j0) = r;
}

// ---- Phase B: persistent h-recurrence. 256 blocks x 512 thr.
// block = (xcd 8, jsub 4, bchunk 8): 32 j cols x 8 batch rows.
__global__ __launch_bounds__(512, 1) void rnn_persist7(
    const float* __restrict__ dotX,   // [512][64][1024]
    const float* __restrict__ WThh,   // [j][k]
    float* __restrict__ hb0,
    float* __restrict__ hb1,
    unsigned int* __restrict__ cnt,   // 8 bchunk counters, 128B apart
    float* __restrict__ out)
{
#pragma clang fp contract(off)
    __shared__ float lds_h[8 * LROW];
    __shared__ float pl[2][8][32];    // [half][b][jl]

    const int xcd    = blockIdx.x & 7;
    const int jsub   = (blockIdx.x >> 3) & 3;
    const int bchunk = blockIdx.x >> 5;        // 0..7
    const int tid  = threadIdx.x;
    const int jl   = tid & 31;
    const int b    = (tid >> 5) & 7;
    const int half = tid >> 8;                 // wave-uniform
    const int jbase = xcd * 128 + jsub * 32;   // WThh slice 128KB/block, 512KB/XCD
    const int j     = jbase + jl;

    const float* wrow = WThh + (size_t)j * HID + half * 512;
    float* hb[2] = { hb0, hb1 };
    unsigned int* mycnt = &cnt[bchunk * 32];

    for (int t = 0; t < TSTEPS; ++t) {
        // prefetch this block's dotX slice (128..256 floats; read-only)
        float dxv = 0.0f;
        if (tid < 256) {
            const int cb = tid >> 5, cj = tid & 31;
            dxv = dotX[(size_t)t * NELEM + (size_t)(bchunk * 8 + cb) * HID
                       + jbase + cj];
        }

        // group barrier: 32 blocks of this bchunk at step t
        if (t > 0) {
            if (tid == 0) {
                const unsigned target = 32u * (unsigned)t;
                while (__hip_atomic_load(mycnt, __ATOMIC_RELAXED,
                                         __HIP_MEMORY_SCOPE_AGENT) < target)
                    __builtin_amdgcn_s_sleep(1);
            }
            __syncthreads();

            // stage h (8 rows) via 32-bit device-scope loads
            const float* hsrc = hb[t & 1] + (size_t)(bchunk * 8) * HID;
            float hv[16];
            #pragma unroll
            for (int u = 0; u < 16; ++u) {
                const int i = tid + u * 512;       // dword 0..8191
                const int r = i >> 10, k = i & 1023;
                hv[u] = __hip_atomic_load(&hsrc[(size_t)r * HID + k],
                                          __ATOMIC_RELAXED,
                                          __HIP_MEMORY_SCOPE_AGENT);
            }
            #pragma unroll
            for (int u = 0; u < 16; ++u) {
                const int i = tid + u * 512;
                const int r = i >> 10, k = i & 1023;
                lds_h[r * LROW + k] = hv[u];
            }
        }
        __syncthreads();

        // h-chain (frozen): acc over k in [half*512, half*512+512), ascending
        float acc = 0.0f;
        if (t > 0) {
            const float* hrow = lds_h + b * LROW + half * 512;
            const float4* w4 = (const float4*)wrow;
            #pragma unroll 4
            for (int kq = 0; kq < 128; ++kq) {
                const float4 w = w4[kq];
                const int k = kq * 4;
                acc = __builtin_fmaf(hrow[k + 0], w.x, acc);
                acc = __builtin_fmaf(hrow[k + 1], w.y, acc);
                acc = __builtin_fmaf(hrow[k + 2], w.z, acc);
                acc = __builtin_fmaf(hrow[k + 3], w.w, acc);
            }
        }
        pl[half][b][jl] = acc;
        __syncthreads();

        // combine (frozen order) + publish
        if (tid < 256) {
            const int cb = tid >> 5, cj = tid & 31;
            const float dotH = pl[0][cb][cj] + pl[1][cb][cj];   // ch0 + ch1
            const float hv = tanh_T2(dxv + dotH);
            const size_t o = (size_t)(bchunk * 8 + cb) * HID + jbase + cj;
            if (t + 1 < TSTEPS)
                __hip_atomic_store(&hb[(t + 1) & 1][o], hv, __ATOMIC_RELAXED,
                                   __HIP_MEMORY_SCOPE_AGENT);
            else
                out[o] = hv;
        }
        __syncthreads();   // vmcnt drain: h stores complete before arrival

        if (t + 1 < TSTEPS && tid == 0)
            __hip_atomic_fetch_add(mycnt, 1u, __ATOMIC_RELAXED,
                                   __HIP_MEMORY_SCOPE_AGENT);
    }
}

// ---- fallback: R15 persistent kernel (proven 16.3ms), needs ~8.9MB ----
__global__ __launch_bounds__(256, 2) void rnn_persist5(
    const float* __restrict__ x, const float* __restrict__ WTih,
    const float* __restrict__ WThh, float* __restrict__ hb0,
    float* __restrict__ hb1, unsigned int* __restrict__ cnt,
    float* __restrict__ out)
{
#pragma clang fp contract(off)
    __shared__ float lds_x[8 * LROW];
    __shared__ float lds_h[8 * LROW];
    __shared__ float pl[4][8][16];

    const int slice  = blockIdx.x & 7;
    const int wid    = blockIdx.x >> 3;
    const int bchunk = wid >> 3;
    const int jchunk = wid & 7;
    const int tid  = threadIdx.x;
    const int jl   = tid & 15;
    const int bp   = (tid >> 4) & 3;
    const int half = (tid >> 6) & 1;
    const int mat  = tid >> 7;
    const int jglob = slice * 128 + jchunk * 16 + jl;
    const int b0 = 2 * bp;

    const float* wrow = ((mat == 0) ? WTih : WThh)
                      + (size_t)jglob * HID + half * 512;
    float* hb[2] = { hb0, hb1 };
    unsigned int* mycnt = &cnt[bchunk * 32];

    for (int t = 0; t < TSTEPS; ++t) {
        float4 xv[8];
        {
            const float* xsrc = x + (size_t)t * NELEM
                              + (size_t)(bchunk * 8) * HID;
            #pragma unroll
            for (int u = 0; u < 8; ++u) {
                const int i = tid + u * 256;
                const int r = i >> 8, c4 = i & 255;
                xv[u] = ((const float4*)(xsrc + (size_t)r * HID))[c4];
            }
        }
        if (t > 0) {
            if (tid == 0) {
                const unsigned target = 64u * (unsigned)t;
                while (__hip_atomic_load(mycnt, __ATOMIC_RELAXED,
                                         __HIP_MEMORY_SCOPE_AGENT) < target)
                    __builtin_amdgcn_s_sleep(1);
            }
            __syncthreads();
        }
        #pragma unroll
        for (int u = 0; u < 8; ++u) {
            const int i = tid + u * 256;
            const int r = i >> 8, c4 = i & 255;
            *(float4*)&lds_x[r * LROW + c4 * 4] = xv[u];
        }
        if (t > 0) {
            const float* hsrc = hb[t & 1] + (size_t)(bchunk * 8) * HID;
            for (int blk = 0; blk < 4; ++blk) {
                float hv[8];
                #pragma unroll
                for (int u = 0; u < 8; ++u) {
                    const int i = tid + (blk * 8 + u) * 256;
                    const int r = i >> 10, k = i & 1023;
                    hv[u] = __hip_atomic_load(&hsrc[(size_t)r * HID + k],
                                              __ATOMIC_RELAXED,
                                              __HIP_MEMORY_SCOPE_AGENT);
                }
                #pragma unroll
                for (int u = 0; u < 8; ++u) {
                    const int i = tid + (blk * 8 + u) * 256;
                    const int r = i >> 10, k = i & 1023;
                    lds_h[r * LROW + k] = hv[u];
                }
            }
        }
        __syncthreads();

        float acc0 = 0.0f, acc1 = 0.0f;
        if (mat == 0 || t > 0) {
            const float* base = (mat == 0) ? lds_x : lds_h;
            const float* oa = base + b0 * LROW;
            const float* ob = base + (b0 + 1) * LROW;
            const float4* w4 = (const float4*)wrow;
            const int kbase = half * 512;
            #pragma unroll 4
            for (int kq = 0; kq < 128; ++kq) {
                const float4 w = w4[kq];
                const int k = kbase + kq * 4;
                acc0 = __builtin_fmaf(oa[k + 0], w.x, acc0);
                acc1 = __builtin_fmaf(ob[k + 0], w.x, acc1);
                acc0 = __builtin_fmaf(oa[k + 1], w.y, acc0);
                acc1 = __builtin_fmaf(ob[k + 1], w.y, acc1);
                acc0 = __builtin_fmaf(oa[k + 2], w.z, acc0);
                acc1 = __builtin_fmaf(ob[k + 2], w.z, acc1);
                acc0 = __builtin_fmaf(oa[k + 3], w.w, acc0);
                acc1 = __builtin_fmaf(ob[k + 3], w.w, acc1);
            }
        }
        pl[mat * 2 + half][b0][jl]     = acc0;
        pl[mat * 2 + half][b0 + 1][jl] = acc1;
        __syncthreads();

        if (tid < 128) {
            const int b = tid >> 4, j = tid & 15;
            const float dotX = pl[0][b][j] + pl[1][b][j];
            const float dotH = pl[2][b][j] + pl[3][b][j];
            const float hv = tanh_T2(dotX + dotH);
            const size_t o = (size_t)(bchunk * 8 + b) * HID
                           + (size_t)slice * 128 + (size_t)jchunk * 16 + j;
            if (t + 1 < TSTEPS)
                __hip_atomic_store(&hb[(t + 1) & 1][o], hv, __ATOMIC_RELAXED,
                                   __HIP_MEMORY_SCOPE_AGENT);
            else
                out[o] = hv;
        }
        __syncthreads();

        if (t + 1 < TSTEPS && tid == 0)
            __hip_atomic_fetch_add(mycnt, 1u, __ATOMIC_RELAXED,
                                   __HIP_MEMORY_SCOPE_AGENT);
    }
}

extern "C" void kernel_launch(void* const* d_in, const int* in_sizes, int n_in,
                              void* d_out, int out_size, void* d_ws, size_t ws_size,
                              hipStream_t stream) {
    const float* x   = (const float*)d_in[0];
    const float* Wih = (const float*)d_in[1];
    const float* Whh = (const float*)d_in[2];
    float* out = (float*)d_out;

    const size_t dotX_f = (size_t)TSTEPS * NELEM;         // 33.5M floats
    const size_t wT_f   = (size_t)HID * HID;              // 1M floats
    const size_t need_new = (dotX_f + wT_f + 2 * (size_t)NELEM) * sizeof(float)
                          + 8 * 32 * sizeof(unsigned int);   // ~139 MB
    const size_t need_old = (2 * wT_f + 2 * (size_t)NELEM) * sizeof(float)
                          + 8 * 32 * sizeof(unsigned int);   // ~8.9 MB

    if (ws_size >= need_new) {
        float* dotX = (float*)d_ws;
        float* WThh = dotX + dotX_f;
        float* hb0  = WThh + wT_f;
        float* hb1  = hb0 + NELEM;
        unsigned int* cnt = (unsigned int*)(hb1 + NELEM);

        transpose_w<<<dim3(16, 16), 256, 0, stream>>>(Whh, WThh);
        gemm_x<<<dim3(16, 4, TSTEPS), 256, 0, stream>>>(x, Wih, dotX);
        hipMemsetAsync(cnt, 0, 8 * 32 * sizeof(unsigned int), stream);
        rnn_persist7<<<dim3(256), dim3(512), 0, stream>>>(
            dotX, WThh, hb0, hb1, cnt, out);
    } else {   // proven R15 path (ws >= 8.9MB established in R12-R16)
        float* WTih = (float*)d_ws;
        float* WThh = WTih + wT_f;
        float* hb0  = WThh + wT_f;
        float* hb1  = hb0 + NELEM;
        unsigned int* cnt = (unsigned int*)(hb1 + NELEM);

        transpose_w<<<dim3(16, 16), 256, 0, stream>>>(Wih, WTih);
        transpose_w<<<dim3(16, 16), 256, 0, stream>>>(Whh, WThh);
        hipMemsetAsync(cnt, 0, 8 * 32 * sizeof(unsigned int), stream);
        rnn_persist5<<<dim3(512), dim3(256), 0, stream>>>(
            x, WTih, WThh, hb0, hb1, cnt, out);
    }
}